// Round 12
// baseline (545.344 us; speedup 1.0000x reference)
//
#include <hip/hip_runtime.h>
#include <string.h>

// Exact k-th order statistic + mask, fp32, n = 64*1024*1024.
// Fast-primitive-only design:
//   winhist : full read, ONE unconditional LDS atomic/elem; 16256-value static
//             window hist (full threshold resolution) + per-lane below counts
//   verify_select : exact rank-window verification + bin select -> st[9]
//   mask_kernel : proven compare+store pass (ungated; both paths write st[9])
//   fallback : proven 3-pass radix select, always enqueued, flag-gated
//
// state: [2]=below [3]=flag [9]=thr float bits [10..15]=fb chain
// ws ints: ST(32) | H(16256) | FB1(4096) | FB2(4096) | FB3(256)   <- zeroed

#define N_STATE 32
#define NBINS   16256
#define H_OFF   32
#define FB1_OFF (H_OFF + NBINS)
#define FB2_OFF (FB1_OFF + 4096)
#define FB3_OFF (FB2_OFF + 4096)
#define FIXED_Z (FB3_OFF + 256)

#define FB_WS_INTS (16 + 4096 + 4096 + 256)

__device__ __forceinline__ unsigned map_bits(unsigned raw) {
    return (raw & 0x80000000u) ? ~raw : (raw | 0x80000000u);
}

// ---------------- workspace zeroing ----------------
__global__ void __launch_bounds__(256)
zero_ws(uint4* __restrict__ p, int n16)
{
    int i = blockIdx.x * 256 + threadIdx.x;
    int s = gridDim.x * 256;
    uint4 z = make_uint4(0u, 0u, 0u, 0u);
    for (; i < n16; i += s) p[i] = z;
}

// ---------------- k1: windowed full-resolution histogram ----------------
// hist_pass shape: per element exactly one unconditional LDS atomic.
__global__ void __launch_bounds__(1024)
winhist(const uint4* __restrict__ x, int n4, unsigned* __restrict__ h,
        unsigned* __restrict__ st, unsigned u0)
{
    __shared__ unsigned lh[NBINS + 64];       // bins + per-lane below-counters
    const unsigned lane = threadIdx.x & 63u;
    for (int i = threadIdx.x; i < NBINS + 64; i += 1024) lh[i] = 0u;
    __syncthreads();

    const unsigned hi_u = u0 + (unsigned)NBINS;
    int idx = blockIdx.x * 1024 + threadIdx.x;
    int S = gridDim.x * 1024;
    for (int i = idx; i < n4; i += S) {
        uint4 v = x[i];
        unsigned u, d, slot, val;
        u = map_bits(v.x); d = u - u0;
        slot = (d < (unsigned)NBINS) ? d : ((unsigned)NBINS + lane);
        val  = (u < hi_u) ? 1u : 0u;
        atomicAdd(&lh[slot], val);
        u = map_bits(v.y); d = u - u0;
        slot = (d < (unsigned)NBINS) ? d : ((unsigned)NBINS + lane);
        val  = (u < hi_u) ? 1u : 0u;
        atomicAdd(&lh[slot], val);
        u = map_bits(v.z); d = u - u0;
        slot = (d < (unsigned)NBINS) ? d : ((unsigned)NBINS + lane);
        val  = (u < hi_u) ? 1u : 0u;
        atomicAdd(&lh[slot], val);
        u = map_bits(v.w); d = u - u0;
        slot = (d < (unsigned)NBINS) ? d : ((unsigned)NBINS + lane);
        val  = (u < hi_u) ? 1u : 0u;
        atomicAdd(&lh[slot], val);
    }
    __syncthreads();
    for (int i = threadIdx.x; i < NBINS + 64; i += 1024) {
        unsigned c = lh[i];
        if (c) {
            if (i < NBINS) atomicAdd(&h[i], c);
            else atomicAdd(&st[2], c);        // exact #{u < u0}
        }
    }
}

// ---------------- exact verification + select -> float thr bits ----------
__global__ void __launch_bounds__(1024)
verify_select(const unsigned* __restrict__ h, unsigned n, unsigned r,
              unsigned u0, unsigned* __restrict__ st)
{
    __shared__ unsigned s[1024];
    __shared__ unsigned sh_r2, sh_flag;
    int t = threadIdx.x;
    unsigned loc[16];
    unsigned mySum = 0;
    int base = t * 16;                        // 16384 slots >= NBINS
    #pragma unroll
    for (int j = 0; j < 16; ++j) {
        int b = base + j;
        loc[j] = (b < NBINS) ? h[b] : 0u;
        mySum += loc[j];
    }
    s[t] = mySum;
    __syncthreads();
    for (int off = 1; off < 1024; off <<= 1) {
        unsigned v = (t >= off) ? s[t - off] : 0u;
        __syncthreads();
        s[t] += v;
        __syncthreads();
    }
    unsigned Nc = s[1023];
    if (t == 0) {
        unsigned long long below = st[2];
        unsigned flag = 0;
        if (!((below <= (unsigned long long)r) &&
              ((unsigned long long)r < below + (unsigned long long)Nc))) flag = 1;
        st[3] = flag;
        sh_flag = flag;
        sh_r2 = (unsigned)((unsigned long long)r - below);
    }
    __syncthreads();
    if (sh_flag != 0u) return;
    unsigned rank = sh_r2;
    unsigned incl = s[t], excl = incl - mySum;
    if (rank >= excl && rank < incl) {
        unsigned run = excl;
        #pragma unroll
        for (int j = 0; j < 16; ++j) {
            if (rank < run + loc[j]) {
                unsigned u = u0 + (unsigned)(base + j);
                st[9] = (u & 0x80000000u) ? (u & 0x7FFFFFFFu) : ~u;  // inverse map
                break;
            }
            run += loc[j];
        }
    }
}

// ---------------- fallback (proven 3-pass radix), flag-gated ----------------
__global__ void __launch_bounds__(256)
hist_pass(const uint4* __restrict__ x, int n4, int shift, int nbins, int mode,
          const unsigned* __restrict__ state, unsigned* __restrict__ hist,
          const unsigned* __restrict__ gate)
{
    if (gate && *gate == 0u) return;
    __shared__ unsigned lh[4096];
    for (int i = threadIdx.x; i < nbins; i += blockDim.x) lh[i] = 0u;
    __syncthreads();

    unsigned tgt = 0; int mshift = 0;
    if (mode == 1)      { tgt = state[0];                      mshift = 20; }
    else if (mode == 2) { tgt = (state[0] << 12) | state[2];   mshift = 8;  }

    const unsigned binmask = (unsigned)(nbins - 1);
    int idx = blockIdx.x * blockDim.x + threadIdx.x;
    int stride = gridDim.x * blockDim.x;
    for (int i = idx; i < n4; i += stride) {
        uint4 v = x[i];
        unsigned u;
        u = map_bits(v.x); if (!mode || (u >> mshift) == tgt) atomicAdd(&lh[(u >> shift) & binmask], 1u);
        u = map_bits(v.y); if (!mode || (u >> mshift) == tgt) atomicAdd(&lh[(u >> shift) & binmask], 1u);
        u = map_bits(v.z); if (!mode || (u >> mshift) == tgt) atomicAdd(&lh[(u >> shift) & binmask], 1u);
        u = map_bits(v.w); if (!mode || (u >> mshift) == tgt) atomicAdd(&lh[(u >> shift) & binmask], 1u);
    }
    __syncthreads();
    for (int i = threadIdx.x; i < nbins; i += blockDim.x) {
        unsigned c = lh[i];
        if (c) atomicAdd(&hist[i], c);
    }
}

__global__ void __launch_bounds__(1024)
scan_select(const unsigned* __restrict__ hist, int nbins,
            const unsigned* __restrict__ rank_in, unsigned rank_imm,
            unsigned* __restrict__ bin_out, unsigned* __restrict__ rank_out,
            const unsigned* __restrict__ gate, int want_nonzero)
{
    if (gate) {
        unsigned g = *gate;
        if ((g != 0u) != (want_nonzero != 0)) return;
    }
    __shared__ unsigned s[1024];
    int t = threadIdx.x;
    unsigned rank = rank_in ? *rank_in : rank_imm;
    int per = (nbins + 1023) >> 10;
    int base = t * per;
    unsigned mySum = 0;
    for (int i = 0; i < per; ++i) {
        int b = base + i;
        if (b < nbins) mySum += hist[b];
    }
    s[t] = mySum;
    __syncthreads();
    for (int off = 1; off < 1024; off <<= 1) {
        unsigned v = (t >= off) ? s[t - off] : 0u;
        __syncthreads();
        s[t] += v;
        __syncthreads();
    }
    unsigned incl = s[t];
    unsigned excl = incl - mySum;
    if (rank >= excl && rank < incl) {
        unsigned run = excl;
        for (int i = 0; i < per; ++i) {
            int b = base + i;
            unsigned c = (b < nbins) ? hist[b] : 0u;
            if (rank < run + c) { *bin_out = (unsigned)b; *rank_out = rank - run; break; }
            run += c;
        }
    }
}

__global__ void finalize_thr_fb(unsigned* st, const unsigned* gate) {
    if (gate && *gate == 0u) return;
    unsigned u = (st[10] << 20) | (st[12] << 8) | st[14];
    st[9] = (u & 0x80000000u) ? (u & 0x7FFFFFFFu) : ~u;
}

// ---------------- final mask (proven kernel, ungated) ----------------
__global__ void __launch_bounds__(256)
mask_kernel(const float4* __restrict__ x, float4* __restrict__ out, int n4,
            const unsigned* __restrict__ st)
{
    float thr = __uint_as_float(st[9]);
    int idx = blockIdx.x * blockDim.x + threadIdx.x;
    int stride = gridDim.x * blockDim.x;
    for (int i = idx; i < n4; i += stride) {
        float4 v = x[i];
        float4 o;
        o.x = (v.x >= thr) ? 1.0f : 0.0f;
        o.y = (v.y >= thr) ? 1.0f : 0.0f;
        o.z = (v.z >= thr) ? 1.0f : 0.0f;
        o.w = (v.w >= thr) ? 1.0f : 0.0f;
        out[i] = o;
    }
}

// ---------------- host ----------------
static inline unsigned host_map(float f) {
    unsigned raw; memcpy(&raw, &f, 4);
    return (raw & 0x80000000u) ? ~raw : (raw | 0x80000000u);
}

extern "C" void kernel_launch(void* const* d_in, const int* in_sizes, int n_in,
                              void* d_out, int out_size, void* d_ws, size_t ws_size,
                              hipStream_t stream)
{
    const float* x = (const float*)d_in[0];
    float* out = (float*)d_out;
    long long n = (long long)in_sizes[0];
    long long k = (long long)((double)n * 0.9);   // matches Python int(n * RATIO)

    if (k <= 0) {
        hipMemsetAsync(d_out, 0, (size_t)out_size * sizeof(float), stream);
        return;
    }

    unsigned* ws = (unsigned*)d_ws;
    unsigned* st = ws;
    int n4 = (int)(n / 4);
    const uint4* x4 = (const uint4*)x;
    unsigned r = (unsigned)(n - k);               // ascending rank of threshold

    size_t need_fast = (size_t)FIXED_Z * 4;

    if (ws_size >= need_fast) {
        unsigned* h   = ws + H_OFF;
        unsigned* fb1 = ws + FB1_OFF;
        unsigned* fb2 = ws + FB2_OFF;
        unsigned* fb3 = ws + FB3_OFF;

        // Static window centered on the 0.1-quantile of N(0,1): 16256 u-values
        // = +-8128 ulp ~= +-4.6 sigma of the sample-quantile position.
        // Exactness does NOT depend on it: flag-verified, fallback-gated.
        unsigned u0 = host_map(-1.2816f) - (unsigned)(NBINS / 2);

        zero_ws<<<64, 256, 0, stream>>>((uint4*)d_ws, (FIXED_Z + 3) / 4);
        winhist<<<512, 1024, 0, stream>>>(x4, n4, h, st, u0);
        verify_select<<<1, 1024, 0, stream>>>(h, (unsigned)n, r, u0, st);
        // fallback chain (gated on flag!=0) — proven exact path, writes st[9]
        hist_pass<<<1024, 256, 0, stream>>>(x4, n4, 20, 4096, 0, &st[10], fb1, &st[3]);
        scan_select<<<1, 1024, 0, stream>>>(fb1, 4096, nullptr, r, &st[10], &st[11], &st[3], 1);
        hist_pass<<<1024, 256, 0, stream>>>(x4, n4, 8, 4096, 1, &st[10], fb2, &st[3]);
        scan_select<<<1, 1024, 0, stream>>>(fb2, 4096, &st[11], 0u, &st[12], &st[13], &st[3], 1);
        hist_pass<<<1024, 256, 0, stream>>>(x4, n4, 0, 256, 2, &st[10], fb3, &st[3]);
        scan_select<<<1, 1024, 0, stream>>>(fb3, 256, &st[13], 0u, &st[14], &st[15], &st[3], 1);
        finalize_thr_fb<<<1, 1, 0, stream>>>(st, &st[3]);
        // final mask for BOTH paths (st[9] written by exactly one of them)
        mask_kernel<<<2048, 256, 0, stream>>>((const float4*)x, (float4*)out, n4, st);
    } else {
        // small-ws standalone fallback: 3-pass radix + mask (ungated)
        unsigned* h1 = ws + 16;
        unsigned* h2 = ws + 16 + 4096;
        unsigned* h3 = ws + 16 + 8192;

        hipMemsetAsync(d_ws, 0, FB_WS_INTS * sizeof(unsigned), stream);

        hist_pass<<<2048, 256, 0, stream>>>(x4, n4, 20, 4096, 0, &ws[10], h1, nullptr);
        scan_select<<<1, 1024, 0, stream>>>(h1, 4096, nullptr, r, &ws[10], &ws[11], nullptr, 0);
        hist_pass<<<2048, 256, 0, stream>>>(x4, n4, 8, 4096, 1, &ws[10], h2, nullptr);
        scan_select<<<1, 1024, 0, stream>>>(h2, 4096, &ws[11], 0u, &ws[12], &ws[13], nullptr, 0);
        hist_pass<<<2048, 256, 0, stream>>>(x4, n4, 0, 256, 2, &ws[10], h3, nullptr);
        scan_select<<<1, 1024, 0, stream>>>(h3, 256, &ws[13], 0u, &ws[14], &ws[15], nullptr, 0);
        finalize_thr_fb<<<1, 1, 0, stream>>>(ws, nullptr);
        mask_kernel<<<2048, 256, 0, stream>>>((const float4*)x, (float4*)out, n4, ws);
    }
}

// Round 13
// 218.147 us; speedup vs baseline: 2.4999x; 2.4999x over previous
//
#include <hip/hip_runtime.h>
#include <string.h>

// Exact k-th order statistic + mask, fp32, n = 64*1024*1024.
// Fast-shape design (all per-element work is spread-address LDS atomics):
//   k1_winhist : coarse 4096-bin LDS hist (anchor CDF, unconditional)
//                + in-B1 256-granularity LDS hist (2% fire)
//                + 1-ulp window global hist (0.03% fire, 16384 bins)
//   anchor_select : exact anchor + verification + window select -> st[9]
//   mask_kernel : proven compare+store pass (ungated)
//   fallback : proven 3-pass radix select, always enqueued, flag-gated
//
// state: [3]=flag [9]=thr float bits [10..15]=fb chain
// ws ints: ST(32)|G12(4096)|G20(4096)|HWIN(16384)|FB1(4096)|FB2(4096)|FB3(256)

#define N_STATE  32
#define G12_OFF  32
#define G20_OFF  (G12_OFF + 4096)
#define HWIN_OFF (G20_OFF + 4096)
#define NWIN     16384
#define FB1_OFF  (HWIN_OFF + NWIN)
#define FB2_OFF  (FB1_OFF + 4096)
#define FB3_OFF  (FB2_OFF + 4096)
#define FIXED_Z  (FB3_OFF + 256)              // ~132 KB zeroed per call

#define FB_WS_INTS (16 + 4096 + 4096 + 256)

__device__ __forceinline__ unsigned map_bits(unsigned raw) {
    return (raw & 0x80000000u) ? ~raw : (raw | 0x80000000u);
}

// ---------------- workspace zeroing ----------------
__global__ void __launch_bounds__(256)
zero_ws(uint4* __restrict__ p, int n16)
{
    int i = blockIdx.x * 256 + threadIdx.x;
    int s = gridDim.x * 256;
    uint4 z = make_uint4(0u, 0u, 0u, 0u);
    for (; i < n16; i += s) p[i] = z;
}

// ---------------- k1: coarse + in-bin + window histograms ----------------
__global__ void __launch_bounds__(256)
k1_winhist(const uint4* __restrict__ x, int n4,
           unsigned* __restrict__ g12, unsigned* __restrict__ g20,
           unsigned* __restrict__ hwin, unsigned B1, unsigned u0)
{
    __shared__ unsigned c12[4096];
    __shared__ unsigned c20[4096];
    for (int i = threadIdx.x; i < 4096; i += 256) { c12[i] = 0u; c20[i] = 0u; }
    __syncthreads();

    int idx = blockIdx.x * 256 + threadIdx.x;
    int S = gridDim.x * 256;
    for (int i = idx; i < n4; i += S) {
        uint4 v = x[i];
        unsigned u;
        #define STEP(COMP) { \
            u = map_bits(v.COMP); \
            atomicAdd(&c12[u >> 20], 1u); \
            if ((u >> 20) == B1) atomicAdd(&c20[(u >> 8) & 4095u], 1u); \
            if ((u - u0) < (unsigned)NWIN) atomicAdd(&hwin[u - u0], 1u); }
        STEP(x) STEP(y) STEP(z) STEP(w)
        #undef STEP
    }
    __syncthreads();
    for (int i = threadIdx.x; i < 4096; i += 256) {
        unsigned a = c12[i];
        if (a) atomicAdd(&g12[i], a);
        unsigned b = c20[i];
        if (b) atomicAdd(&g20[i], b);
    }
}

// ---------------- exact anchor + verification + window select ----------------
__global__ void __launch_bounds__(1024)
anchor_select(const unsigned* __restrict__ g12, const unsigned* __restrict__ g20,
              const unsigned* __restrict__ hwin, unsigned r,
              unsigned B1, unsigned s0, unsigned u0, unsigned* __restrict__ st)
{
    __shared__ unsigned s[1024];
    __shared__ unsigned sh_below, sh_rank, sh_flag;
    int t = threadIdx.x;

    // phase 1: below = sum_{b<B1} g12[b] + sum_{sb<s0} g20[sb]
    unsigned part = 0;
    for (int j = t; j < 4096; j += 1024) {
        if ((unsigned)j < B1) part += g12[j];
        if ((unsigned)j < s0) part += g20[j];
    }
    s[t] = part;
    __syncthreads();
    for (int off = 512; off > 0; off >>= 1) {
        if (t < off) s[t] += s[t + off];
        __syncthreads();
    }
    if (t == 0) sh_below = s[0];
    __syncthreads();

    // phase 2: prefix over hwin (16 bins/thread)
    unsigned loc[16];
    unsigned mySum = 0;
    int base = t * 16;
    #pragma unroll
    for (int j = 0; j < 16; ++j) { loc[j] = hwin[base + j]; mySum += loc[j]; }
    s[t] = mySum;
    __syncthreads();
    for (int off = 1; off < 1024; off <<= 1) {
        unsigned v = (t >= off) ? s[t - off] : 0u;
        __syncthreads();
        s[t] += v;
        __syncthreads();
    }
    unsigned Nwin = s[1023];
    if (t == 0) {
        unsigned long long below = sh_below;
        unsigned flag = 0;
        if (!((below <= (unsigned long long)r) &&
              ((unsigned long long)r < below + (unsigned long long)Nwin))) flag = 1;
        st[3] = flag;
        sh_flag = flag;
        sh_rank = (unsigned)((unsigned long long)r - below);
    }
    __syncthreads();
    if (sh_flag != 0u) return;
    unsigned rank = sh_rank;
    unsigned incl = s[t], excl = incl - mySum;
    if (rank >= excl && rank < incl) {
        unsigned run = excl;
        #pragma unroll
        for (int j = 0; j < 16; ++j) {
            if (rank < run + loc[j]) {
                unsigned u = u0 + (unsigned)(base + j);
                st[9] = (u & 0x80000000u) ? (u & 0x7FFFFFFFu) : ~u;  // inverse map
                break;
            }
            run += loc[j];
        }
    }
}

// ---------------- fallback (proven 3-pass radix), flag-gated ----------------
__global__ void __launch_bounds__(256)
hist_pass(const uint4* __restrict__ x, int n4, int shift, int nbins, int mode,
          const unsigned* __restrict__ state, unsigned* __restrict__ hist,
          const unsigned* __restrict__ gate)
{
    if (gate && *gate == 0u) return;
    __shared__ unsigned lh[4096];
    for (int i = threadIdx.x; i < nbins; i += blockDim.x) lh[i] = 0u;
    __syncthreads();

    unsigned tgt = 0; int mshift = 0;
    if (mode == 1)      { tgt = state[0];                      mshift = 20; }
    else if (mode == 2) { tgt = (state[0] << 12) | state[2];   mshift = 8;  }

    const unsigned binmask = (unsigned)(nbins - 1);
    int idx = blockIdx.x * blockDim.x + threadIdx.x;
    int stride = gridDim.x * blockDim.x;
    for (int i = idx; i < n4; i += stride) {
        uint4 v = x[i];
        unsigned u;
        u = map_bits(v.x); if (!mode || (u >> mshift) == tgt) atomicAdd(&lh[(u >> shift) & binmask], 1u);
        u = map_bits(v.y); if (!mode || (u >> mshift) == tgt) atomicAdd(&lh[(u >> shift) & binmask], 1u);
        u = map_bits(v.z); if (!mode || (u >> mshift) == tgt) atomicAdd(&lh[(u >> shift) & binmask], 1u);
        u = map_bits(v.w); if (!mode || (u >> mshift) == tgt) atomicAdd(&lh[(u >> shift) & binmask], 1u);
    }
    __syncthreads();
    for (int i = threadIdx.x; i < nbins; i += blockDim.x) {
        unsigned c = lh[i];
        if (c) atomicAdd(&hist[i], c);
    }
}

__global__ void __launch_bounds__(1024)
scan_select(const unsigned* __restrict__ hist, int nbins,
            const unsigned* __restrict__ rank_in, unsigned rank_imm,
            unsigned* __restrict__ bin_out, unsigned* __restrict__ rank_out,
            const unsigned* __restrict__ gate, int want_nonzero)
{
    if (gate) {
        unsigned g = *gate;
        if ((g != 0u) != (want_nonzero != 0)) return;
    }
    __shared__ unsigned s[1024];
    int t = threadIdx.x;
    unsigned rank = rank_in ? *rank_in : rank_imm;
    int per = (nbins + 1023) >> 10;
    int base = t * per;
    unsigned mySum = 0;
    for (int i = 0; i < per; ++i) {
        int b = base + i;
        if (b < nbins) mySum += hist[b];
    }
    s[t] = mySum;
    __syncthreads();
    for (int off = 1; off < 1024; off <<= 1) {
        unsigned v = (t >= off) ? s[t - off] : 0u;
        __syncthreads();
        s[t] += v;
        __syncthreads();
    }
    unsigned incl = s[t];
    unsigned excl = incl - mySum;
    if (rank >= excl && rank < incl) {
        unsigned run = excl;
        for (int i = 0; i < per; ++i) {
            int b = base + i;
            unsigned c = (b < nbins) ? hist[b] : 0u;
            if (rank < run + c) { *bin_out = (unsigned)b; *rank_out = rank - run; break; }
            run += c;
        }
    }
}

__global__ void finalize_thr_fb(unsigned* st, const unsigned* gate) {
    if (gate && *gate == 0u) return;
    unsigned u = (st[10] << 20) | (st[12] << 8) | st[14];
    st[9] = (u & 0x80000000u) ? (u & 0x7FFFFFFFu) : ~u;
}

// ---------------- final mask (proven kernel, ungated) ----------------
__global__ void __launch_bounds__(256)
mask_kernel(const float4* __restrict__ x, float4* __restrict__ out, int n4,
            const unsigned* __restrict__ st)
{
    float thr = __uint_as_float(st[9]);
    int idx = blockIdx.x * blockDim.x + threadIdx.x;
    int stride = gridDim.x * blockDim.x;
    for (int i = idx; i < n4; i += stride) {
        float4 v = x[i];
        float4 o;
        o.x = (v.x >= thr) ? 1.0f : 0.0f;
        o.y = (v.y >= thr) ? 1.0f : 0.0f;
        o.z = (v.z >= thr) ? 1.0f : 0.0f;
        o.w = (v.w >= thr) ? 1.0f : 0.0f;
        out[i] = o;
    }
}

// ---------------- host ----------------
static inline unsigned host_map(float f) {
    unsigned raw; memcpy(&raw, &f, 4);
    return (raw & 0x80000000u) ? ~raw : (raw | 0x80000000u);
}

extern "C" void kernel_launch(void* const* d_in, const int* in_sizes, int n_in,
                              void* d_out, int out_size, void* d_ws, size_t ws_size,
                              hipStream_t stream)
{
    const float* x = (const float*)d_in[0];
    float* out = (float*)d_out;
    long long n = (long long)in_sizes[0];
    long long k = (long long)((double)n * 0.9);   // matches Python int(n * RATIO)

    if (k <= 0) {
        hipMemsetAsync(d_out, 0, (size_t)out_size * sizeof(float), stream);
        return;
    }

    unsigned* ws = (unsigned*)d_ws;
    unsigned* st = ws;
    int n4 = (int)(n / 4);
    const uint4* x4 = (const uint4*)x;
    unsigned r = (unsigned)(n - k);               // ascending rank of threshold

    size_t need_fast = (size_t)FIXED_Z * 4;

    if (ws_size >= need_fast) {
        unsigned* g12  = ws + G12_OFF;
        unsigned* g20  = ws + G20_OFF;
        unsigned* hwin = ws + HWIN_OFF;
        unsigned* fb1  = ws + FB1_OFF;
        unsigned* fb2  = ws + FB2_OFF;
        unsigned* fb3  = ws + FB3_OFF;

        // Static geometry around the 0.1-quantile of N(0,1), u* = map(-1.2816):
        //  B1  : 2^20-wide coarse bin of u* (margin 150 sigma, r10-verified)
        //  u0  : 256-aligned window start, window = 16384 ulp ~ +-4.7 sigma
        //  s0  : u0's 256-granularity sub-bin index within B1
        // Exactness NEVER depends on these: flag-verified, fallback-gated.
        unsigned ustar = host_map(-1.2816f);
        unsigned B1 = ustar >> 20;
        unsigned u0 = (ustar - (unsigned)(NWIN / 2)) & ~255u;
        unsigned s0 = (u0 >> 8) & 4095u;

        zero_ws<<<64, 256, 0, stream>>>((uint4*)d_ws, (FIXED_Z + 3) / 4);
        k1_winhist<<<2048, 256, 0, stream>>>(x4, n4, g12, g20, hwin, B1, u0);
        anchor_select<<<1, 1024, 0, stream>>>(g12, g20, hwin, r, B1, s0, u0, st);
        // fallback chain (gated on flag!=0) — proven exact path, writes st[9]
        hist_pass<<<1024, 256, 0, stream>>>(x4, n4, 20, 4096, 0, &st[10], fb1, &st[3]);
        scan_select<<<1, 1024, 0, stream>>>(fb1, 4096, nullptr, r, &st[10], &st[11], &st[3], 1);
        hist_pass<<<1024, 256, 0, stream>>>(x4, n4, 8, 4096, 1, &st[10], fb2, &st[3]);
        scan_select<<<1, 1024, 0, stream>>>(fb2, 4096, &st[11], 0u, &st[12], &st[13], &st[3], 1);
        hist_pass<<<1024, 256, 0, stream>>>(x4, n4, 0, 256, 2, &st[10], fb3, &st[3]);
        scan_select<<<1, 1024, 0, stream>>>(fb3, 256, &st[13], 0u, &st[14], &st[15], &st[3], 1);
        finalize_thr_fb<<<1, 1, 0, stream>>>(st, &st[3]);
        // final mask for BOTH paths (st[9] written by exactly one of them)
        mask_kernel<<<2048, 256, 0, stream>>>((const float4*)x, (float4*)out, n4, st);
    } else {
        // small-ws standalone fallback: 3-pass radix + mask (ungated)
        unsigned* h1 = ws + 16;
        unsigned* h2 = ws + 16 + 4096;
        unsigned* h3 = ws + 16 + 8192;

        hipMemsetAsync(d_ws, 0, FB_WS_INTS * sizeof(unsigned), stream);

        hist_pass<<<2048, 256, 0, stream>>>(x4, n4, 20, 4096, 0, &ws[10], h1, nullptr);
        scan_select<<<1, 1024, 0, stream>>>(h1, 4096, nullptr, r, &ws[10], &ws[11], nullptr, 0);
        hist_pass<<<2048, 256, 0, stream>>>(x4, n4, 8, 4096, 1, &ws[10], h2, nullptr);
        scan_select<<<1, 1024, 0, stream>>>(h2, 4096, &ws[11], 0u, &ws[12], &ws[13], nullptr, 0);
        hist_pass<<<2048, 256, 0, stream>>>(x4, n4, 0, 256, 2, &ws[10], h3, nullptr);
        scan_select<<<1, 1024, 0, stream>>>(h3, 256, &ws[13], 0u, &ws[14], &ws[15], nullptr, 0);
        finalize_thr_fb<<<1, 1, 0, stream>>>(ws, nullptr);
        mask_kernel<<<2048, 256, 0, stream>>>((const float4*)x, (float4*)out, n4, ws);
    }
}

// Round 14
// 155.368 us; speedup vs baseline: 3.5100x; 1.4041x over previous
//
#include <hip/hip_runtime.h>
#include <string.h>

// Exact k-th order statistic + mask, fp32, n = 64*1024*1024.
// Fused single-full-pass design (r13's proven fast shape + mask store):
//   k1_fused : read x, write PROVISIONAL mask (u >= u0+NWIN), coarse c12 LDS
//              hist, in-B1 c20 LDS hist (2% fire), 1-ulp window global hist +
//              per-block compaction (0.035% fire, wave-skippable branch,
//              per-block LDS slot counter)
//   anchor_select : exact anchor/verify + window select -> thr (st[8]/st[9])
//   fixup : scatter 1.0f for the ~23K window elems >= thr (gated flag==0)
//   fallback : proven 3-pass radix + FULL re-mask, always enqueued, flag-gated
//
// state: [3]=flag [8]=thr mapped-u [9]=thr float bits [10..15]=fb chain
// ws ints: ST(32)|G12(4096)|G20(4096)|HWIN(16384)|FB1(4096)|FB2(4096)|FB3(256)
//          |CNTB(2048)  <- all zeroed | CAND(2048 blocks x 256 x uint2)

#define N_STATE  32
#define G12_OFF  32
#define G20_OFF  (G12_OFF + 4096)
#define HWIN_OFF (G20_OFF + 4096)
#define NWIN     16384
#define FB1_OFF  (HWIN_OFF + NWIN)
#define FB2_OFF  (FB1_OFF + 4096)
#define FB3_OFF  (FB2_OFF + 4096)
#define CNTB_OFF (FB3_OFF + 256)
#define NBLK     2048
#define FIXED_Z  (CNTB_OFF + NBLK)            // ~140 KB zeroed per call
#define CAND_OFF FIXED_Z
#define BSEG     256u

#define FB_WS_INTS (16 + 4096 + 4096 + 256)

__device__ __forceinline__ unsigned map_bits(unsigned raw) {
    return (raw & 0x80000000u) ? ~raw : (raw | 0x80000000u);
}

// ---------------- workspace zeroing ----------------
__global__ void __launch_bounds__(256)
zero_ws(uint4* __restrict__ p, int n16)
{
    int i = blockIdx.x * 256 + threadIdx.x;
    int s = gridDim.x * 256;
    uint4 z = make_uint4(0u, 0u, 0u, 0u);
    for (; i < n16; i += s) p[i] = z;
}

// ---------------- k1: fused mask + histograms + block compaction ----------
__global__ void __launch_bounds__(256)
k1_fused(const uint4* __restrict__ x, int n4, float4* __restrict__ out,
         unsigned* __restrict__ g12, unsigned* __restrict__ g20,
         unsigned* __restrict__ hwin, uint2* __restrict__ cand,
         unsigned* __restrict__ cntb, unsigned B1, unsigned u0)
{
    __shared__ unsigned c12[4096];
    __shared__ unsigned c20[4096];
    __shared__ unsigned bcnt;
    for (int i = threadIdx.x; i < 4096; i += 256) { c12[i] = 0u; c20[i] = 0u; }
    if (threadIdx.x == 0) bcnt = 0u;
    __syncthreads();

    uint2* seg = cand + (size_t)blockIdx.x * BSEG;
    const unsigned hiw = u0 + (unsigned)NWIN;
    int idx = blockIdx.x * 256 + threadIdx.x;
    int S = gridDim.x * 256;
    for (int i = idx; i < n4; i += S) {
        uint4 v = x[i];
        float4 o;
        unsigned gi = (unsigned)i * 4u;
        unsigned u;
        #define STEP(C, OFS, OC) { \
            u = map_bits(v.C); \
            OC = (u >= hiw) ? 1.0f : 0.0f; \
            atomicAdd(&c12[u >> 20], 1u); \
            if ((u >> 20) == B1) atomicAdd(&c20[(u >> 8) & 4095u], 1u); \
            if ((u - u0) < (unsigned)NWIN) { \
                atomicAdd(&hwin[u - u0], 1u); \
                unsigned slot = atomicAdd(&bcnt, 1u); \
                if (slot < BSEG) seg[slot] = make_uint2(u, gi + OFS); } }
        STEP(x, 0u, o.x) STEP(y, 1u, o.y) STEP(z, 2u, o.z) STEP(w, 3u, o.w)
        #undef STEP
        out[i] = o;
    }
    __syncthreads();
    for (int i = threadIdx.x; i < 4096; i += 256) {
        unsigned a = c12[i];
        if (a) atomicAdd(&g12[i], a);
        unsigned b = c20[i];
        if (b) atomicAdd(&g20[i], b);
    }
    if (threadIdx.x == 0) cntb[blockIdx.x] = bcnt;
}

// ---------------- exact anchor + verification + window select ----------------
__global__ void __launch_bounds__(1024)
anchor_select(const unsigned* __restrict__ g12, const unsigned* __restrict__ g20,
              const unsigned* __restrict__ hwin, const unsigned* __restrict__ cntb,
              unsigned r, unsigned B1, unsigned s0, unsigned u0,
              unsigned* __restrict__ st)
{
    __shared__ unsigned s[1024];
    __shared__ unsigned sm[1024];
    __shared__ unsigned sh_below, sh_rank, sh_flag, sh_max;
    int t = threadIdx.x;

    // phase 0+1: below-anchor sum AND per-block-count max
    unsigned part = 0;
    for (int j = t; j < 4096; j += 1024) {
        if ((unsigned)j < B1) part += g12[j];
        if ((unsigned)j < s0) part += g20[j];
    }
    unsigned mx = 0;
    for (int j = t; j < NBLK; j += 1024) {
        unsigned c = cntb[j];
        mx = (c > mx) ? c : mx;
    }
    s[t] = part; sm[t] = mx;
    __syncthreads();
    for (int off = 512; off > 0; off >>= 1) {
        if (t < off) {
            s[t] += s[t + off];
            sm[t] = (sm[t + off] > sm[t]) ? sm[t + off] : sm[t];
        }
        __syncthreads();
    }
    if (t == 0) { sh_below = s[0]; sh_max = sm[0]; }
    __syncthreads();

    // phase 2: prefix over hwin (16 bins/thread)
    unsigned loc[16];
    unsigned mySum = 0;
    int base = t * 16;
    #pragma unroll
    for (int j = 0; j < 16; ++j) { loc[j] = hwin[base + j]; mySum += loc[j]; }
    s[t] = mySum;
    __syncthreads();
    for (int off = 1; off < 1024; off <<= 1) {
        unsigned v = (t >= off) ? s[t - off] : 0u;
        __syncthreads();
        s[t] += v;
        __syncthreads();
    }
    unsigned Nwin = s[1023];
    if (t == 0) {
        unsigned long long below = sh_below;
        unsigned flag = 0;
        if (sh_max > BSEG) flag = 1;          // block segment overflow
        if (!((below <= (unsigned long long)r) &&
              ((unsigned long long)r < below + (unsigned long long)Nwin))) flag = 1;
        st[3] = flag;
        sh_flag = flag;
        sh_rank = (unsigned)((unsigned long long)r - below);
    }
    __syncthreads();
    if (sh_flag != 0u) return;
    unsigned rank = sh_rank;
    unsigned incl = s[t], excl = incl - mySum;
    if (rank >= excl && rank < incl) {
        unsigned run = excl;
        #pragma unroll
        for (int j = 0; j < 16; ++j) {
            if (rank < run + loc[j]) {
                unsigned u = u0 + (unsigned)(base + j);
                st[8] = u;                                            // mapped thr
                st[9] = (u & 0x80000000u) ? (u & 0x7FFFFFFFu) : ~u;   // float bits
                break;
            }
            run += loc[j];
        }
    }
}

// ---------------- fixup (gated flag==0) ----------------
__global__ void __launch_bounds__(64)
fixup(const uint2* __restrict__ cand, const unsigned* __restrict__ cntb,
      const unsigned* __restrict__ st, float* __restrict__ out)
{
    if (st[3] != 0u) return;
    unsigned thr = st[8];
    unsigned b = blockIdx.x;
    unsigned m = cntb[b]; if (m > BSEG) m = BSEG;
    const uint2* seg = cand + (size_t)b * BSEG;
    for (unsigned j = threadIdx.x; j < m; j += 64u) {
        uint2 cv = seg[j];
        if (cv.x >= thr) out[cv.y] = 1.0f;
    }
}

// ---------------- fallback (proven 3-pass radix), flag-gated ----------------
__global__ void __launch_bounds__(256)
hist_pass(const uint4* __restrict__ x, int n4, int shift, int nbins, int mode,
          const unsigned* __restrict__ state, unsigned* __restrict__ hist,
          const unsigned* __restrict__ gate)
{
    if (gate && *gate == 0u) return;
    __shared__ unsigned lh[4096];
    for (int i = threadIdx.x; i < nbins; i += blockDim.x) lh[i] = 0u;
    __syncthreads();

    unsigned tgt = 0; int mshift = 0;
    if (mode == 1)      { tgt = state[0];                      mshift = 20; }
    else if (mode == 2) { tgt = (state[0] << 12) | state[2];   mshift = 8;  }

    const unsigned binmask = (unsigned)(nbins - 1);
    int idx = blockIdx.x * blockDim.x + threadIdx.x;
    int stride = gridDim.x * blockDim.x;
    for (int i = idx; i < n4; i += stride) {
        uint4 v = x[i];
        unsigned u;
        u = map_bits(v.x); if (!mode || (u >> mshift) == tgt) atomicAdd(&lh[(u >> shift) & binmask], 1u);
        u = map_bits(v.y); if (!mode || (u >> mshift) == tgt) atomicAdd(&lh[(u >> shift) & binmask], 1u);
        u = map_bits(v.z); if (!mode || (u >> mshift) == tgt) atomicAdd(&lh[(u >> shift) & binmask], 1u);
        u = map_bits(v.w); if (!mode || (u >> mshift) == tgt) atomicAdd(&lh[(u >> shift) & binmask], 1u);
    }
    __syncthreads();
    for (int i = threadIdx.x; i < nbins; i += blockDim.x) {
        unsigned c = lh[i];
        if (c) atomicAdd(&hist[i], c);
    }
}

__global__ void __launch_bounds__(1024)
scan_select(const unsigned* __restrict__ hist, int nbins,
            const unsigned* __restrict__ rank_in, unsigned rank_imm,
            unsigned* __restrict__ bin_out, unsigned* __restrict__ rank_out,
            const unsigned* __restrict__ gate, int want_nonzero)
{
    if (gate) {
        unsigned g = *gate;
        if ((g != 0u) != (want_nonzero != 0)) return;
    }
    __shared__ unsigned s[1024];
    int t = threadIdx.x;
    unsigned rank = rank_in ? *rank_in : rank_imm;
    int per = (nbins + 1023) >> 10;
    int base = t * per;
    unsigned mySum = 0;
    for (int i = 0; i < per; ++i) {
        int b = base + i;
        if (b < nbins) mySum += hist[b];
    }
    s[t] = mySum;
    __syncthreads();
    for (int off = 1; off < 1024; off <<= 1) {
        unsigned v = (t >= off) ? s[t - off] : 0u;
        __syncthreads();
        s[t] += v;
        __syncthreads();
    }
    unsigned incl = s[t];
    unsigned excl = incl - mySum;
    if (rank >= excl && rank < incl) {
        unsigned run = excl;
        for (int i = 0; i < per; ++i) {
            int b = base + i;
            unsigned c = (b < nbins) ? hist[b] : 0u;
            if (rank < run + c) { *bin_out = (unsigned)b; *rank_out = rank - run; break; }
            run += c;
        }
    }
}

__global__ void finalize_thr_fb(unsigned* st, const unsigned* gate) {
    if (gate && *gate == 0u) return;
    unsigned u = (st[10] << 20) | (st[12] << 8) | st[14];
    st[9] = (u & 0x80000000u) ? (u & 0x7FFFFFFFu) : ~u;
}

// ---------------- full re-mask (fallback path only, flag-gated) ------------
__global__ void __launch_bounds__(256)
mask_kernel(const float4* __restrict__ x, float4* __restrict__ out, int n4,
            const unsigned* __restrict__ st, const unsigned* __restrict__ gate)
{
    if (gate && *gate == 0u) return;
    float thr = __uint_as_float(st[9]);
    int idx = blockIdx.x * blockDim.x + threadIdx.x;
    int stride = gridDim.x * blockDim.x;
    for (int i = idx; i < n4; i += stride) {
        float4 v = x[i];
        float4 o;
        o.x = (v.x >= thr) ? 1.0f : 0.0f;
        o.y = (v.y >= thr) ? 1.0f : 0.0f;
        o.z = (v.z >= thr) ? 1.0f : 0.0f;
        o.w = (v.w >= thr) ? 1.0f : 0.0f;
        out[i] = o;
    }
}

// ---------------- host ----------------
static inline unsigned host_map(float f) {
    unsigned raw; memcpy(&raw, &f, 4);
    return (raw & 0x80000000u) ? ~raw : (raw | 0x80000000u);
}

extern "C" void kernel_launch(void* const* d_in, const int* in_sizes, int n_in,
                              void* d_out, int out_size, void* d_ws, size_t ws_size,
                              hipStream_t stream)
{
    const float* x = (const float*)d_in[0];
    float* out = (float*)d_out;
    long long n = (long long)in_sizes[0];
    long long k = (long long)((double)n * 0.9);   // matches Python int(n * RATIO)

    if (k <= 0) {
        hipMemsetAsync(d_out, 0, (size_t)out_size * sizeof(float), stream);
        return;
    }

    unsigned* ws = (unsigned*)d_ws;
    unsigned* st = ws;
    int n4 = (int)(n / 4);
    const uint4* x4 = (const uint4*)x;
    unsigned r = (unsigned)(n - k);               // ascending rank of threshold

    size_t need_fast = ((size_t)CAND_OFF + (size_t)NBLK * BSEG * 2) * 4;

    if (ws_size >= need_fast) {
        unsigned* g12  = ws + G12_OFF;
        unsigned* g20  = ws + G20_OFF;
        unsigned* hwin = ws + HWIN_OFF;
        unsigned* fb1  = ws + FB1_OFF;
        unsigned* fb2  = ws + FB2_OFF;
        unsigned* fb3  = ws + FB3_OFF;
        unsigned* cntb = ws + CNTB_OFF;
        uint2*    cand = (uint2*)(ws + CAND_OFF);

        // Static geometry around the 0.1-quantile of N(0,1), u* = map(-1.2816):
        //  B1 : 2^20-wide coarse bin of u* ; u0 : 256-aligned window start,
        //  window = 16384 ulp ~= +-4.7 sigma of the sample-quantile position;
        //  s0 : u0's 256-granularity sub-bin within B1.
        // Exactness NEVER depends on these: flag-verified, fallback-gated.
        unsigned ustar = host_map(-1.2816f);
        unsigned B1 = ustar >> 20;
        unsigned u0 = (ustar - (unsigned)(NWIN / 2)) & ~255u;
        unsigned s0 = (u0 >> 8) & 4095u;

        zero_ws<<<64, 256, 0, stream>>>((uint4*)d_ws, (FIXED_Z + 3) / 4);
        k1_fused<<<NBLK, 256, 0, stream>>>(x4, n4, (float4*)out, g12, g20,
                                           hwin, cand, cntb, B1, u0);
        anchor_select<<<1, 1024, 0, stream>>>(g12, g20, hwin, cntb, r, B1, s0, u0, st);
        fixup<<<NBLK, 64, 0, stream>>>(cand, cntb, st, out);
        // fallback chain (gated on flag!=0) — proven exact path, writes st[9]
        hist_pass<<<1024, 256, 0, stream>>>(x4, n4, 20, 4096, 0, &st[10], fb1, &st[3]);
        scan_select<<<1, 1024, 0, stream>>>(fb1, 4096, nullptr, r, &st[10], &st[11], &st[3], 1);
        hist_pass<<<1024, 256, 0, stream>>>(x4, n4, 8, 4096, 1, &st[10], fb2, &st[3]);
        scan_select<<<1, 1024, 0, stream>>>(fb2, 4096, &st[11], 0u, &st[12], &st[13], &st[3], 1);
        hist_pass<<<1024, 256, 0, stream>>>(x4, n4, 0, 256, 2, &st[10], fb3, &st[3]);
        scan_select<<<1, 1024, 0, stream>>>(fb3, 256, &st[13], 0u, &st[14], &st[15], &st[3], 1);
        finalize_thr_fb<<<1, 1, 0, stream>>>(st, &st[3]);
        mask_kernel<<<2048, 256, 0, stream>>>((const float4*)x, (float4*)out, n4, st, &st[3]);
    } else {
        // small-ws standalone fallback: 3-pass radix + mask (ungated)
        unsigned* h1 = ws + 16;
        unsigned* h2 = ws + 16 + 4096;
        unsigned* h3 = ws + 16 + 8192;

        hipMemsetAsync(d_ws, 0, FB_WS_INTS * sizeof(unsigned), stream);

        hist_pass<<<2048, 256, 0, stream>>>(x4, n4, 20, 4096, 0, &ws[10], h1, nullptr);
        scan_select<<<1, 1024, 0, stream>>>(h1, 4096, nullptr, r, &ws[10], &ws[11], nullptr, 0);
        hist_pass<<<2048, 256, 0, stream>>>(x4, n4, 8, 4096, 1, &ws[10], h2, nullptr);
        scan_select<<<1, 1024, 0, stream>>>(h2, 4096, &ws[11], 0u, &ws[12], &ws[13], nullptr, 0);
        hist_pass<<<2048, 256, 0, stream>>>(x4, n4, 0, 256, 2, &ws[10], h3, nullptr);
        scan_select<<<1, 1024, 0, stream>>>(h3, 256, &ws[13], 0u, &ws[14], &ws[15], nullptr, 0);
        finalize_thr_fb<<<1, 1, 0, stream>>>(ws, nullptr);
        mask_kernel<<<2048, 256, 0, stream>>>((const float4*)x, (float4*)out, n4, ws, nullptr);
    }
}

// Round 15
// 150.793 us; speedup vs baseline: 3.6165x; 1.0303x over previous
//
#include <hip/hip_runtime.h>
#include <string.h>

// Exact k-th order statistic + mask, fp32, n = 64*1024*1024.
// Fused single-full-pass, histogram work gated on p <= B1 (10.5% fire):
//   k1_fused : read x, write PROVISIONAL mask (u >= u0+NWIN);
//              for p<=B1 only: coarse c12 LDS hist, in-B1 c20 LDS hist,
//              1-ulp window global hist + per-block compaction
//   anchor_select : exact anchor/verify + window select -> thr (st[8]/st[9])
//   fixup : scatter 1.0f for the ~23K window elems >= thr (gated flag==0)
//   fallback : proven 3-pass radix + FULL re-mask, always enqueued, flag-gated
//
// state: [3]=flag [8]=thr mapped-u [9]=thr float bits [10..15]=fb chain
// ws ints: ST(32)|G12(4096)|G20(4096)|HWIN(16384)|FB1(4096)|FB2(4096)|FB3(256)
//          |CNTB(2048)  <- all zeroed | CAND(2048 blocks x 256 x uint2)

#define N_STATE  32
#define G12_OFF  32
#define G20_OFF  (G12_OFF + 4096)
#define HWIN_OFF (G20_OFF + 4096)
#define NWIN     16384
#define FB1_OFF  (HWIN_OFF + NWIN)
#define FB2_OFF  (FB1_OFF + 4096)
#define FB3_OFF  (FB2_OFF + 4096)
#define CNTB_OFF (FB3_OFF + 256)
#define NBLK     2048
#define FIXED_Z  (CNTB_OFF + NBLK)            // ~140 KB zeroed per call
#define CAND_OFF FIXED_Z
#define BSEG     256u

#define FB_WS_INTS (16 + 4096 + 4096 + 256)

__device__ __forceinline__ unsigned map_bits(unsigned raw) {
    return (raw & 0x80000000u) ? ~raw : (raw | 0x80000000u);
}

// ---------------- workspace zeroing ----------------
__global__ void __launch_bounds__(256)
zero_ws(uint4* __restrict__ p, int n16)
{
    int i = blockIdx.x * 256 + threadIdx.x;
    int s = gridDim.x * 256;
    uint4 z = make_uint4(0u, 0u, 0u, 0u);
    for (; i < n16; i += s) p[i] = z;
}

// ---------------- k1: fused mask + gated histograms + compaction ----------
__global__ void __launch_bounds__(256)
k1_fused(const uint4* __restrict__ x, int n4, float4* __restrict__ out,
         unsigned* __restrict__ g12, unsigned* __restrict__ g20,
         unsigned* __restrict__ hwin, uint2* __restrict__ cand,
         unsigned* __restrict__ cntb, unsigned B1, unsigned u0)
{
    __shared__ unsigned c12[4096];
    __shared__ unsigned c20[4096];
    __shared__ unsigned bcnt;
    for (int i = threadIdx.x; i < 4096; i += 256) { c12[i] = 0u; c20[i] = 0u; }
    if (threadIdx.x == 0) bcnt = 0u;
    __syncthreads();

    uint2* seg = cand + (size_t)blockIdx.x * BSEG;
    const unsigned hiw = u0 + (unsigned)NWIN;
    int idx = blockIdx.x * 256 + threadIdx.x;
    int S = gridDim.x * 256;
    for (int i = idx; i < n4; i += S) {
        uint4 v = x[i];
        float4 o;
        unsigned gi = (unsigned)i * 4u;
        unsigned u, p;
        #define STEP(C, OFS, OC) { \
            u = map_bits(v.C); p = u >> 20; \
            OC = (u >= hiw) ? 1.0f : 0.0f; \
            if (p <= B1) { \
                atomicAdd(&c12[p], 1u); \
                if (p == B1) { \
                    atomicAdd(&c20[(u >> 8) & 4095u], 1u); \
                    if ((u - u0) < (unsigned)NWIN) { \
                        atomicAdd(&hwin[u - u0], 1u); \
                        unsigned slot = atomicAdd(&bcnt, 1u); \
                        if (slot < BSEG) seg[slot] = make_uint2(u, gi + OFS); } } } }
        STEP(x, 0u, o.x) STEP(y, 1u, o.y) STEP(z, 2u, o.z) STEP(w, 3u, o.w)
        #undef STEP
        out[i] = o;
    }
    __syncthreads();
    for (int i = threadIdx.x; i < 4096; i += 256) {
        unsigned a = c12[i];
        if (a) atomicAdd(&g12[i], a);
        unsigned b = c20[i];
        if (b) atomicAdd(&g20[i], b);
    }
    if (threadIdx.x == 0) cntb[blockIdx.x] = bcnt;
}

// ---------------- exact anchor + verification + window select ----------------
__global__ void __launch_bounds__(1024)
anchor_select(const unsigned* __restrict__ g12, const unsigned* __restrict__ g20,
              const unsigned* __restrict__ hwin, const unsigned* __restrict__ cntb,
              unsigned r, unsigned B1, unsigned s0, unsigned u0,
              unsigned* __restrict__ st)
{
    __shared__ unsigned s[1024];
    __shared__ unsigned sm[1024];
    __shared__ unsigned sh_below, sh_rank, sh_flag, sh_max;
    int t = threadIdx.x;

    // phase 0+1: below-anchor sum AND per-block-count max
    unsigned part = 0;
    for (int j = t; j < 4096; j += 1024) {
        if ((unsigned)j < B1) part += g12[j];
        if ((unsigned)j < s0) part += g20[j];
    }
    unsigned mx = 0;
    for (int j = t; j < NBLK; j += 1024) {
        unsigned c = cntb[j];
        mx = (c > mx) ? c : mx;
    }
    s[t] = part; sm[t] = mx;
    __syncthreads();
    for (int off = 512; off > 0; off >>= 1) {
        if (t < off) {
            s[t] += s[t + off];
            sm[t] = (sm[t + off] > sm[t]) ? sm[t + off] : sm[t];
        }
        __syncthreads();
    }
    if (t == 0) { sh_below = s[0]; sh_max = sm[0]; }
    __syncthreads();

    // phase 2: prefix over hwin (16 bins/thread)
    unsigned loc[16];
    unsigned mySum = 0;
    int base = t * 16;
    #pragma unroll
    for (int j = 0; j < 16; ++j) { loc[j] = hwin[base + j]; mySum += loc[j]; }
    s[t] = mySum;
    __syncthreads();
    for (int off = 1; off < 1024; off <<= 1) {
        unsigned v = (t >= off) ? s[t - off] : 0u;
        __syncthreads();
        s[t] += v;
        __syncthreads();
    }
    unsigned Nwin = s[1023];
    if (t == 0) {
        unsigned long long below = sh_below;
        unsigned flag = 0;
        if (sh_max > BSEG) flag = 1;          // block segment overflow
        if (!((below <= (unsigned long long)r) &&
              ((unsigned long long)r < below + (unsigned long long)Nwin))) flag = 1;
        st[3] = flag;
        sh_flag = flag;
        sh_rank = (unsigned)((unsigned long long)r - below);
    }
    __syncthreads();
    if (sh_flag != 0u) return;
    unsigned rank = sh_rank;
    unsigned incl = s[t], excl = incl - mySum;
    if (rank >= excl && rank < incl) {
        unsigned run = excl;
        #pragma unroll
        for (int j = 0; j < 16; ++j) {
            if (rank < run + loc[j]) {
                unsigned u = u0 + (unsigned)(base + j);
                st[8] = u;                                            // mapped thr
                st[9] = (u & 0x80000000u) ? (u & 0x7FFFFFFFu) : ~u;   // float bits
                break;
            }
            run += loc[j];
        }
    }
}

// ---------------- fixup (gated flag==0) ----------------
__global__ void __launch_bounds__(64)
fixup(const uint2* __restrict__ cand, const unsigned* __restrict__ cntb,
      const unsigned* __restrict__ st, float* __restrict__ out)
{
    if (st[3] != 0u) return;
    unsigned thr = st[8];
    unsigned b = blockIdx.x;
    unsigned m = cntb[b]; if (m > BSEG) m = BSEG;
    const uint2* seg = cand + (size_t)b * BSEG;
    for (unsigned j = threadIdx.x; j < m; j += 64u) {
        uint2 cv = seg[j];
        if (cv.x >= thr) out[cv.y] = 1.0f;
    }
}

// ---------------- fallback (proven 3-pass radix), flag-gated ----------------
__global__ void __launch_bounds__(256)
hist_pass(const uint4* __restrict__ x, int n4, int shift, int nbins, int mode,
          const unsigned* __restrict__ state, unsigned* __restrict__ hist,
          const unsigned* __restrict__ gate)
{
    if (gate && *gate == 0u) return;
    __shared__ unsigned lh[4096];
    for (int i = threadIdx.x; i < nbins; i += blockDim.x) lh[i] = 0u;
    __syncthreads();

    unsigned tgt = 0; int mshift = 0;
    if (mode == 1)      { tgt = state[0];                      mshift = 20; }
    else if (mode == 2) { tgt = (state[0] << 12) | state[2];   mshift = 8;  }

    const unsigned binmask = (unsigned)(nbins - 1);
    int idx = blockIdx.x * blockDim.x + threadIdx.x;
    int stride = gridDim.x * blockDim.x;
    for (int i = idx; i < n4; i += stride) {
        uint4 v = x[i];
        unsigned u;
        u = map_bits(v.x); if (!mode || (u >> mshift) == tgt) atomicAdd(&lh[(u >> shift) & binmask], 1u);
        u = map_bits(v.y); if (!mode || (u >> mshift) == tgt) atomicAdd(&lh[(u >> shift) & binmask], 1u);
        u = map_bits(v.z); if (!mode || (u >> mshift) == tgt) atomicAdd(&lh[(u >> shift) & binmask], 1u);
        u = map_bits(v.w); if (!mode || (u >> mshift) == tgt) atomicAdd(&lh[(u >> shift) & binmask], 1u);
    }
    __syncthreads();
    for (int i = threadIdx.x; i < nbins; i += blockDim.x) {
        unsigned c = lh[i];
        if (c) atomicAdd(&hist[i], c);
    }
}

__global__ void __launch_bounds__(1024)
scan_select(const unsigned* __restrict__ hist, int nbins,
            const unsigned* __restrict__ rank_in, unsigned rank_imm,
            unsigned* __restrict__ bin_out, unsigned* __restrict__ rank_out,
            const unsigned* __restrict__ gate, int want_nonzero)
{
    if (gate) {
        unsigned g = *gate;
        if ((g != 0u) != (want_nonzero != 0)) return;
    }
    __shared__ unsigned s[1024];
    int t = threadIdx.x;
    unsigned rank = rank_in ? *rank_in : rank_imm;
    int per = (nbins + 1023) >> 10;
    int base = t * per;
    unsigned mySum = 0;
    for (int i = 0; i < per; ++i) {
        int b = base + i;
        if (b < nbins) mySum += hist[b];
    }
    s[t] = mySum;
    __syncthreads();
    for (int off = 1; off < 1024; off <<= 1) {
        unsigned v = (t >= off) ? s[t - off] : 0u;
        __syncthreads();
        s[t] += v;
        __syncthreads();
    }
    unsigned incl = s[t];
    unsigned excl = incl - mySum;
    if (rank >= excl && rank < incl) {
        unsigned run = excl;
        for (int i = 0; i < per; ++i) {
            int b = base + i;
            unsigned c = (b < nbins) ? hist[b] : 0u;
            if (rank < run + c) { *bin_out = (unsigned)b; *rank_out = rank - run; break; }
            run += c;
        }
    }
}

__global__ void finalize_thr_fb(unsigned* st, const unsigned* gate) {
    if (gate && *gate == 0u) return;
    unsigned u = (st[10] << 20) | (st[12] << 8) | st[14];
    st[9] = (u & 0x80000000u) ? (u & 0x7FFFFFFFu) : ~u;
}

// ---------------- full re-mask (fallback path only, flag-gated) ------------
__global__ void __launch_bounds__(256)
mask_kernel(const float4* __restrict__ x, float4* __restrict__ out, int n4,
            const unsigned* __restrict__ st, const unsigned* __restrict__ gate)
{
    if (gate && *gate == 0u) return;
    float thr = __uint_as_float(st[9]);
    int idx = blockIdx.x * blockDim.x + threadIdx.x;
    int stride = gridDim.x * blockDim.x;
    for (int i = idx; i < n4; i += stride) {
        float4 v = x[i];
        float4 o;
        o.x = (v.x >= thr) ? 1.0f : 0.0f;
        o.y = (v.y >= thr) ? 1.0f : 0.0f;
        o.z = (v.z >= thr) ? 1.0f : 0.0f;
        o.w = (v.w >= thr) ? 1.0f : 0.0f;
        out[i] = o;
    }
}

// ---------------- host ----------------
static inline unsigned host_map(float f) {
    unsigned raw; memcpy(&raw, &f, 4);
    return (raw & 0x80000000u) ? ~raw : (raw | 0x80000000u);
}

extern "C" void kernel_launch(void* const* d_in, const int* in_sizes, int n_in,
                              void* d_out, int out_size, void* d_ws, size_t ws_size,
                              hipStream_t stream)
{
    const float* x = (const float*)d_in[0];
    float* out = (float*)d_out;
    long long n = (long long)in_sizes[0];
    long long k = (long long)((double)n * 0.9);   // matches Python int(n * RATIO)

    if (k <= 0) {
        hipMemsetAsync(d_out, 0, (size_t)out_size * sizeof(float), stream);
        return;
    }

    unsigned* ws = (unsigned*)d_ws;
    unsigned* st = ws;
    int n4 = (int)(n / 4);
    const uint4* x4 = (const uint4*)x;
    unsigned r = (unsigned)(n - k);               // ascending rank of threshold

    size_t need_fast = ((size_t)CAND_OFF + (size_t)NBLK * BSEG * 2) * 4;

    if (ws_size >= need_fast) {
        unsigned* g12  = ws + G12_OFF;
        unsigned* g20  = ws + G20_OFF;
        unsigned* hwin = ws + HWIN_OFF;
        unsigned* fb1  = ws + FB1_OFF;
        unsigned* fb2  = ws + FB2_OFF;
        unsigned* fb3  = ws + FB3_OFF;
        unsigned* cntb = ws + CNTB_OFF;
        uint2*    cand = (uint2*)(ws + CAND_OFF);

        // Static geometry around the 0.1-quantile of N(0,1), u* = map(-1.2816):
        //  B1 : 2^20-wide coarse bin of u* ; u0 : 256-aligned window start,
        //  window = 16384 ulp ~= +-4.7 sigma of the sample-quantile position;
        //  s0 : u0's 256-granularity sub-bin within B1.
        // Exactness NEVER depends on these: flag-verified, fallback-gated.
        unsigned ustar = host_map(-1.2816f);
        unsigned B1 = ustar >> 20;
        unsigned u0 = (ustar - (unsigned)(NWIN / 2)) & ~255u;
        unsigned s0 = (u0 >> 8) & 4095u;

        zero_ws<<<64, 256, 0, stream>>>((uint4*)d_ws, (FIXED_Z + 3) / 4);
        k1_fused<<<NBLK, 256, 0, stream>>>(x4, n4, (float4*)out, g12, g20,
                                           hwin, cand, cntb, B1, u0);
        anchor_select<<<1, 1024, 0, stream>>>(g12, g20, hwin, cntb, r, B1, s0, u0, st);
        fixup<<<NBLK, 64, 0, stream>>>(cand, cntb, st, out);
        // fallback chain (gated on flag!=0) — proven exact path, writes st[9]
        hist_pass<<<1024, 256, 0, stream>>>(x4, n4, 20, 4096, 0, &st[10], fb1, &st[3]);
        scan_select<<<1, 1024, 0, stream>>>(fb1, 4096, nullptr, r, &st[10], &st[11], &st[3], 1);
        hist_pass<<<1024, 256, 0, stream>>>(x4, n4, 8, 4096, 1, &st[10], fb2, &st[3]);
        scan_select<<<1, 1024, 0, stream>>>(fb2, 4096, &st[11], 0u, &st[12], &st[13], &st[3], 1);
        hist_pass<<<1024, 256, 0, stream>>>(x4, n4, 0, 256, 2, &st[10], fb3, &st[3]);
        scan_select<<<1, 1024, 0, stream>>>(fb3, 256, &st[13], 0u, &st[14], &st[15], &st[3], 1);
        finalize_thr_fb<<<1, 1, 0, stream>>>(st, &st[3]);
        mask_kernel<<<2048, 256, 0, stream>>>((const float4*)x, (float4*)out, n4, st, &st[3]);
    } else {
        // small-ws standalone fallback: 3-pass radix + mask (ungated)
        unsigned* h1 = ws + 16;
        unsigned* h2 = ws + 16 + 4096;
        unsigned* h3 = ws + 16 + 8192;

        hipMemsetAsync(d_ws, 0, FB_WS_INTS * sizeof(unsigned), stream);

        hist_pass<<<2048, 256, 0, stream>>>(x4, n4, 20, 4096, 0, &ws[10], h1, nullptr);
        scan_select<<<1, 1024, 0, stream>>>(h1, 4096, nullptr, r, &ws[10], &ws[11], nullptr, 0);
        hist_pass<<<2048, 256, 0, stream>>>(x4, n4, 8, 4096, 1, &ws[10], h2, nullptr);
        scan_select<<<1, 1024, 0, stream>>>(h2, 4096, &ws[11], 0u, &ws[12], &ws[13], nullptr, 0);
        hist_pass<<<2048, 256, 0, stream>>>(x4, n4, 0, 256, 2, &ws[10], h3, nullptr);
        scan_select<<<1, 1024, 0, stream>>>(h3, 256, &ws[13], 0u, &ws[14], &ws[15], nullptr, 0);
        finalize_thr_fb<<<1, 1, 0, stream>>>(ws, nullptr);
        mask_kernel<<<2048, 256, 0, stream>>>((const float4*)x, (float4*)out, n4, ws, nullptr);
    }
}